// Round 2
// baseline (697.274 us; speedup 1.0000x reference)
//
#include <hip/hip_runtime.h>

// Problem constants (B, T, IN, H, OUT) = (256, 128, 128, 256, 128)
// External tensors f32; internal MFMA in bf16 with f32 accumulate; gx
// workspace bf16 PRE-SCALED by log2e (r,z gates) / 2*log2e (n gate) so the
// gate math needs no multiplies before exp2.
//
// Round-7: scan per-step cost attack (3790 cyc -> target ~3000):
//  (a) DPP dedup of h-fragment reads: lanes r/r+8 need identical B-frags;
//      each reads half the kk range (4 ds_read_b128, not 8) and swaps via
//      v_mov_dpp row_ror:8 + cndmask. LDS pipe 128->64 reads/CU/step.
//      kk4-7 block skewed +4 u16 in h_bf rows -> conflict-free reads.
//  (b) Issue order [RZ mfma][N mfma][sigmoid r,z][tail]: r/z transcendentals
//      overlap the N-chain MFMA drain. setprio(1) around MFMA cluster.
//  (c) gx_gemm C-writeback staged through LDS for 16B/lane coalesced stores
//      (was 48x scattered 2B global_store_short per thread on 48 MB).
#define B_   256
#define T_   128
#define IN_  128
#define H_   256
#define H3_  768
#define OUT_ 128

#define L2E  1.4426950408889634f

typedef unsigned short u16;
typedef u16   u16x2  __attribute__((ext_vector_type(2)));
typedef u16   u16x4  __attribute__((ext_vector_type(4)));
typedef u16   u16x8  __attribute__((ext_vector_type(8)));
typedef __bf16 bf16x8 __attribute__((ext_vector_type(8)));
typedef float f32x2  __attribute__((ext_vector_type(2)));
typedef float f32x4  __attribute__((ext_vector_type(4)));
typedef int   i32x4  __attribute__((ext_vector_type(4)));

__device__ __forceinline__ float bf2f(u16 u) {
  unsigned int v = ((unsigned int)u) << 16;
  return __builtin_bit_cast(float, v);
}
__device__ __forceinline__ u16 f2bf(float f) {        // RNE (off hot path)
  unsigned int u = __builtin_bit_cast(unsigned int, f);
  u += 0x7fffu + ((u >> 16) & 1u);
  return (u16)(u >> 16);
}
__device__ __forceinline__ u16 f2bf_fast(float f) {   // round-half-up
  unsigned int u = __builtin_bit_cast(unsigned int, f);
  return (u16)((u + 0x8000u) >> 16);
}
__device__ __forceinline__ f32x4 mfma16(bf16x8 a, bf16x8 b, f32x4 c) {
  return __builtin_amdgcn_mfma_f32_16x16x32_bf16(a, b, c, 0, 0, 0);
}
__device__ __forceinline__ float exp2f_(float x) {
#if __has_builtin(__builtin_amdgcn_exp2f)
  return __builtin_amdgcn_exp2f(x);
#else
  return __builtin_exp2f(x);
#endif
}
__device__ __forceinline__ float rcp_(float x) { return __builtin_amdgcn_rcpf(x); }

// lane l <-> lane l^8 exchange (row_ror:8 within each 16-lane row)
__device__ __forceinline__ bf16x8 dppswap(bf16x8 v) {
  i32x4 a = __builtin_bit_cast(i32x4, v);
  i32x4 b;
  #pragma unroll
  for (int d = 0; d < 4; ++d)
    b[d] = __builtin_amdgcn_update_dpp(0, a[d], 0x128, 0xF, 0xF, true);
  return __builtin_bit_cast(bf16x8, b);
}
__device__ __forceinline__ bf16x8 sel8(bool c, bf16x8 a, bf16x8 b) {
  i32x4 x = __builtin_bit_cast(i32x4, a), y = __builtin_bit_cast(i32x4, b), r;
  #pragma unroll
  for (int d = 0; d < 4; ++d) r[d] = c ? x[d] : y[d];
  return __builtin_bit_cast(bf16x8, r);
}

// ---------------------------------------------------------------------------
// Kernel 1 (fused prep):
//  blocks [0,384):  Wx (f32, 128x768) -> WxT (bf16, 768x128), unscaled
//  blocks [384,480): Wh (f32, 256x768) -> whp: bf16 fragments PRE-PACKED in
//    the exact per-thread order cru_scan consumes (layout is block-invariant)
__global__ __launch_bounds__(256) void prep(const float* __restrict__ Wx,
                                            const float* __restrict__ Wh,
                                            u16* __restrict__ WxT,
                                            u16* __restrict__ whp) {
  const int bid = blockIdx.x;
  if (bid < 384) {
    int o = bid * 256 + threadIdx.x;            // 0..98303
    int n = o >> 7, k = o & 127;
    WxT[o] = f2bf(Wx[(size_t)k * H3_ + n]);
  } else {
    int o8 = (bid - 384) * 256 + threadIdx.x;   // 0..24575 (one u16x8 each)
    int kk = o8 & 7;
    int g  = (o8 >> 3) % 3;
    int tp = o8 / 24;                           // scan-kernel tid, 0..1023
    int l  = tp & 63, w = tp >> 6;
    int n  = g * 256 + w * 16 + (l & 15);
    int rowb = kk * 32 + (((l >> 4) & 3) << 3);
    float sgw = (g < 2) ? L2E : (2.f * L2E);
    u16x8 v;
    #pragma unroll
    for (int j = 0; j < 8; ++j)
      v[j] = f2bf(Wh[(size_t)(rowb + j) * H3_ + n] * sgw);
    *(u16x8*)(whp + (size_t)o8 * 8) = v;
  }
}

// ---------------------------------------------------------------------------
// Kernel 2: gx[t*B+b][n] = bf16( (x[b,t,:]@Wx[:,n] + bx[n] + (n<512?bh[n]:0)) * sc )
// sc = L2E for r/z gates (n<512), 2*L2E for n gate. M=32768, N=768, K=128.
// Tile 128(M) x 192(N), 512 threads (8 waves as 2Mx4N). C staged via LDS.
__global__ __launch_bounds__(512) void gx_gemm(const float* __restrict__ x,
                                               const u16* __restrict__ WxT,
                                               const float* __restrict__ bx,
                                               const float* __restrict__ bh,
                                               u16* __restrict__ gxw) {
  __shared__ __align__(16) char smem[(128 * 136 + 192 * 136) * 2];  // 87 KB
  u16 (*As)[136] = (u16(*)[136])smem;
  u16 (*Bs)[136] = (u16(*)[136])(smem + 128 * 136 * 2);
  u16 (*St)[204] = (u16(*)[204])smem;       // aliases As/Bs after 2nd barrier

  const int mt = blockIdx.x;                  // 0..255
  const int n0 = blockIdx.y * 192;            // 0,192,384,576
  const int m0 = mt * 128;
  const int t  = mt >> 1;
  const int brow0 = (mt & 1) * 128;
  const int tid = threadIdx.x;
  const int w = tid >> 6, lane = tid & 63, quad = lane >> 4, r = lane & 15;
  const int wm = w >> 2, wn = w & 3;          // 2 x 4 wave grid

  {  // A tile: 128 rows x 128 cols, f32 -> bf16
    int row = tid >> 2;
    int colc = (tid & 3) * 32;
    const float* s = x + ((size_t)(brow0 + row) * T_ + t) * IN_ + colc;
    #pragma unroll
    for (int c4 = 0; c4 < 8; ++c4) {
      f32x4 v = *(const f32x4*)(s + c4 * 4);
      u16x4 b;
      b[0] = f2bf(v[0]); b[1] = f2bf(v[1]); b[2] = f2bf(v[2]); b[3] = f2bf(v[3]);
      *(u16x4*)&As[row][colc + c4 * 4] = b;
    }
  }
  {  // B tile [n][k] from WxT: 192 x 128 u16
    #pragma unroll
    for (int i = 0; i < 6; ++i) {
      int idx = tid + i * 512;                // 0..3071
      int row = idx >> 4, col8 = (idx & 15) * 8;
      *(u16x8*)&Bs[row][col8] = *(const u16x8*)(WxT + (size_t)(n0 + row) * IN_ + col8);
    }
  }
  __syncthreads();

  f32x4 acc[4][3];
  #pragma unroll
  for (int i = 0; i < 4; ++i)
    #pragma unroll
    for (int j = 0; j < 3; ++j)
      acc[i][j] = (f32x4){0.f, 0.f, 0.f, 0.f};

  #pragma unroll
  for (int kk = 0; kk < 4; ++kk) {
    bf16x8 a[4];
    #pragma unroll
    for (int m2 = 0; m2 < 4; ++m2)
      a[m2] = *(const bf16x8*)&As[wm * 64 + m2 * 16 + r][kk * 32 + quad * 8];
    #pragma unroll
    for (int n2 = 0; n2 < 3; ++n2) {
      bf16x8 b = *(const bf16x8*)&Bs[wn * 48 + n2 * 16 + r][kk * 32 + quad * 8];
      #pragma unroll
      for (int m2 = 0; m2 < 4; ++m2)
        acc[m2][n2] = mfma16(a[m2], b, acc[m2][n2]);
    }
  }

  __syncthreads();   // all LDS reads done; safe to alias As/Bs as St

  #pragma unroll
  for (int m2 = 0; m2 < 4; ++m2)
    #pragma unroll
    for (int n2 = 0; n2 < 3; ++n2) {
      int nl = wn * 48 + n2 * 16 + r;                  // local col (C col = lane&15)
      int n  = n0 + nl;
      float sc = (n < 512) ? L2E : (2.f * L2E);
      float bias = bx[n] + (n < 512 ? bh[n] : 0.f);
      #pragma unroll
      for (int e = 0; e < 4; ++e) {                    // C row = quad*4 + e
        int mrow = wm * 64 + m2 * 16 + quad * 4 + e;
        St[mrow][nl] = f2bf((acc[m2][n2][e] + bias) * sc);
      }
    }
  __syncthreads();

  #pragma unroll
  for (int i = 0; i < 6; ++i) {                        // coalesced 16B stores
    int idx = tid + i * 512;                           // 0..3071
    int row = idx / 24, c8 = (idx % 24) * 8;
    *(u16x8*)(gxw + (size_t)(m0 + row) * H3_ + n0 + c8) = *(const u16x8*)&St[row][c8];
  }
}

// ---------------------------------------------------------------------------
// Kernel 3: the scan. 96 blocks x 1024 threads (16 waves), 8 batch rows/block.
// h_bf row layout: [cols 0..127][4 pad][cols 128..255][4 pad] (skew so the
// split-kk reads are bank-conflict-free). Lanes r<8 read kk0-3, r>=8 read
// kk4-7; halves exchanged via DPP row_ror:8 + cndmask (VALU, not LDS pipe).
__global__ __launch_bounds__(1024)
void cru_scan(const float* __restrict__ hid,
              const u16*  __restrict__ whp,
              const float* __restrict__ bh,
              const u16*  __restrict__ gx,
              float* __restrict__ hT) {
  __shared__ __align__(16) u16 h_bf[2][8][264];   // double buffer, 8.25 KB

  const int bid = blockIdx.x;           // 96 blocks
  const int c   = bid >> 5;             // component 0..2
  const int b0  = (bid & 31) << 3;      // batch row group of 8
  const int tid = threadIdx.x;
  const int lane = tid & 63, quad = lane >> 4, r = lane & 15;
  const int w  = tid >> 6;              // wave 0..15
  const int rr = r & 7;                 // batch row within group
  const bool hi8 = (r >= 8);
  const int hi = hi8 ? 2 : 0;           // element-pair offset within D slice
  const int cb = w * 16 + quad * 4;     // n-col base within component

  // --- one-time fragment load: 384 B contiguous per thread, coalesced ---
  bf16x8 bfr[3][8];
  {
    const u16* wp = whp + (size_t)tid * 192;
    #pragma unroll
    for (int g = 0; g < 3; ++g)
      #pragma unroll
      for (int kk = 0; kk < 8; ++kk)
        bfr[g][kk] = *(const bf16x8*)(wp + g * 64 + kk * 8);
  }

  // --- this lane's h slice: h[rr][cb+hi .. cb+hi+1] ---
  const int wskew = (cb >= 128) ? 4 : 0;          // skewed col position
  const size_t hrow = (size_t)(c * 256 + b0 + rr) * 256 + cb + hi;
  f32x2 h2 = *(const f32x2*)(hid + hrow);
  float hx = h2[0], hy = h2[1];
  {
    u16x2 hb; hb[0] = f2bf(hx); hb[1] = f2bf(hy);
    *(u16x2*)&h_bf[0][rr][cb + hi + wskew] = hb;
  }
  f32x2 bn2 = *(const f32x2*)(bh + 512 + cb + hi);
  const float bn0 = bn2[0] * (2.f * L2E), bn1 = bn2[1] * (2.f * L2E);

  const u16* gxp = gx + (size_t)(b0 + rr) * H3_ + cb + hi;
  const int rbase = rr * 264 + (hi8 ? 132 : 0) + quad * 8;  // read base (u16)

  __syncthreads();

  #pragma unroll 2
  for (int t = 0; t < T_; ++t) {
    const int sel = t & 1;
    // A) issue this step's gx loads; consumed mid-epilogue
    const u16* src = gxp + (size_t)t * (B_ * H3_);
    u16x2 xr2 = *(const u16x2*)(src);
    u16x2 xz2 = *(const u16x2*)(src + 256);
    u16x2 xn2 = *(const u16x2*)(src + 512);

    // B) read own kk-half (4 x ds_read_b128), swap with lane^8 via DPP
    const u16* hb = &h_bf[sel][0][0];
    bf16x8 own0 = *(const bf16x8*)(hb + rbase);
    bf16x8 own1 = *(const bf16x8*)(hb + rbase + 32);
    bf16x8 own2 = *(const bf16x8*)(hb + rbase + 64);
    bf16x8 own3 = *(const bf16x8*)(hb + rbase + 96);
    bf16x8 sw0 = dppswap(own0), sw1 = dppswap(own1);
    bf16x8 sw2 = dppswap(own2), sw3 = dppswap(own3);
    bf16x8 f0 = sel8(hi8, sw0, own0), f1 = sel8(hi8, sw1, own1);
    bf16x8 f2v = sel8(hi8, sw2, own2), f3 = sel8(hi8, sw3, own3);
    bf16x8 f4 = sel8(hi8, own0, sw0), f5 = sel8(hi8, own1, sw1);
    bf16x8 f6 = sel8(hi8, own2, sw2), f7 = sel8(hi8, own3, sw3);

    // C) gh^T = Wh^T * h^T : R,Z chains first, N chain after
    f32x4 accR = {0.f, 0.f, 0.f, 0.f};
    f32x4 accZ = {0.f, 0.f, 0.f, 0.f};
    f32x4 accN = {0.f, 0.f, 0.f, 0.f};
    __builtin_amdgcn_s_setprio(1);
#define RZ_(j, fj) accR = mfma16(bfr[0][j], fj, accR); \
                   accZ = mfma16(bfr[1][j], fj, accZ);
    RZ_(0, f0)  RZ_(1, f1)  RZ_(2, f2v) RZ_(3, f3)
    RZ_(4, f4)  RZ_(5, f5)  RZ_(6, f6)  RZ_(7, f7)
#undef RZ_
#define N_(j, fj) accN = mfma16(bfr[2][j], fj, accN);
    N_(0, f0)  N_(1, f1)  N_(2, f2v) N_(3, f3)
    N_(4, f4)  N_(5, f5)  N_(6, f6)  N_(7, f7)
#undef N_
    __builtin_amdgcn_s_setprio(0);

    // D) sigmoid r,z issue while the N chain drains the matrix pipe
    float gR0 = hi8 ? accR[2] : accR[0], gR1 = hi8 ? accR[3] : accR[1];
    float gZ0 = hi8 ? accZ[2] : accZ[0], gZ1 = hi8 ? accZ[3] : accZ[1];
    float sr0 = rcp_(1.f + exp2f_(-(bf2f(xr2[0]) + gR0)));
    float sz0 = rcp_(1.f + exp2f_(-(bf2f(xz2[0]) + gZ0)));
    float sr1 = rcp_(1.f + exp2f_(-(bf2f(xr2[1]) + gR1)));
    float sz1 = rcp_(1.f + exp2f_(-(bf2f(xz2[1]) + gZ1)));

    // E) tanh + GRU update
    float gN0 = hi8 ? accN[2] : accN[0], gN1 = hi8 ? accN[3] : accN[1];
    float nv0 = bf2f(xn2[0]) + sr0 * (gN0 + bn0);          // 2*L2E-scaled
    float nn0 = fmaf(2.f, rcp_(1.f + exp2f_(-nv0)), -1.f); // tanh, inf-safe
    float h0  = nn0 + sz0 * (hx - nn0);
    float nv1 = bf2f(xn2[1]) + sr1 * (gN1 + bn1);
    float nn1 = fmaf(2.f, rcp_(1.f + exp2f_(-nv1)), -1.f);
    float h1  = nn1 + sz1 * (hy - nn1);

    hx = h0; hy = h1;
    u16x2 hw; hw[0] = f2bf_fast(h0); hw[1] = f2bf_fast(h1);
    *(u16x2*)&h_bf[sel ^ 1][rr][cb + hi + wskew] = hw;
    __syncthreads();   // h_bf[sel^1] ready; orders next-step reads of it
  }

  f32x2 ho; ho[0] = hx; ho[1] = hy;
  *(f32x2*)(hT + hrow) = ho;
}

// ---------------------------------------------------------------------------
// Kernel 4: out[b] = elu(sum_c hT[c,b,:] @ Wf + bf); feature[c,:] = mean_b hT
__global__ __launch_bounds__(128) void finalize(const float* __restrict__ hT,
                                                const float* __restrict__ Wf,
                                                const float* __restrict__ bfv,
                                                float* __restrict__ out) {
  __shared__ float hsum[256];
  const int bid = blockIdx.x, tid = threadIdx.x;
  if (bid < 256) {
    const int b = bid;
    for (int k = tid; k < 256; k += 128)
      hsum[k] = hT[((size_t)(0 * 256 + b)) * 256 + k]
              + hT[((size_t)(1 * 256 + b)) * 256 + k]
              + hT[((size_t)(2 * 256 + b)) * 256 + k];
    __syncthreads();
    float acc = bfv[tid];
    #pragma unroll 8
    for (int k = 0; k < 256; ++k)
      acc = fmaf(hsum[k], Wf[(size_t)k * OUT_ + tid], acc);
    float rv = acc > 0.f ? acc : (__expf(acc) - 1.f);
    out[b * OUT_ + tid] = rv;
  } else {
    const int idx = bid - 256;                 // 0..5
    const int c = idx >> 1, j = ((idx & 1) << 7) + tid;
    float sum = 0.f;
    #pragma unroll 4
    for (int b = 0; b < 256; ++b)
      sum += hT[((size_t)(c * 256 + b)) * 256 + j];
    out[B_ * OUT_ + c * 256 + j] = sum * (1.f / 256.f);
  }
}

// ---------------------------------------------------------------------------
extern "C" void kernel_launch(void* const* d_in, const int* in_sizes, int n_in,
                              void* d_out, int out_size, void* d_ws, size_t ws_size,
                              hipStream_t stream) {
  const float* x   = (const float*)d_in[0];
  const float* hid = (const float*)d_in[1];
  const float* Wx  = (const float*)d_in[2];
  const float* bx  = (const float*)d_in[3];
  const float* Wh  = (const float*)d_in[4];
  const float* bh  = (const float*)d_in[5];
  const float* Wf  = (const float*)d_in[6];
  const float* bf_ = (const float*)d_in[7];
  float* out = (float*)d_out;

  char* ws = (char*)d_ws;
  u16* WxT   = (u16*)ws;                                   // 768*128 bf16 = 192 KiB
  u16* gxw   = (u16*)(ws + (1 << 18));                     // 128*256*768 bf16 = 48 MiB
  float* hTw = (float*)(ws + (1 << 18) + (size_t)T_ * B_ * H3_ * 2);  // 3*256*256 f32
  u16* whp   = (u16*)(ws + (1 << 18) + (size_t)T_ * B_ * H3_ * 2
                         + (size_t)3 * 256 * 256 * 4);     // 256*768 bf16 = 384 KiB

  prep<<<480, 256, 0, stream>>>(Wx, Wh, WxT, whp);
  gx_gemm<<<dim3(256, 4), 512, 0, stream>>>(x, WxT, bx, bh, gxw);
  cru_scan<<<96, 1024, 0, stream>>>(hid, whp, bh, gxw, hTw);
  finalize<<<262, 128, 0, stream>>>(hTw, Wf, bf_, out);
}

// Round 3
// 301.911 us; speedup vs baseline: 2.3095x; 2.3095x over previous
//
#include <hip/hip_runtime.h>

// Problem constants (B, T, IN, H, OUT) = (256, 128, 128, 256, 128)
// External tensors f32; internal MFMA in bf16 with f32 accumulate; gx
// workspace bf16 PRE-SCALED by log2e (r,z gates) / 2*log2e (n gate) so the
// gate math needs no multiplies before exp2.
//
// Round-8: R2's DPP dedup spilled (own/sw/f0-7 = +64 live VGPRs -> WRITE_SIZE
// 39 MB scratch, 5% MfmaUtil). Revert it. Keep what worked: conflict-free
// skewed h_bf (6.29M -> 0 conflicts) and gx_gemm LDS-staged writeback.
// New lever: batch rows per block R=8 -> 4, grid 96 -> 192 blocks. Blocks are
// independent across the scan; wall time = per-block step time. Per-CU MFMA
// (384/step) is R-invariant, but epilogue VALU, LDS volume and h traffic all
// halve. Lane (l&15)=m owns batch m&3, acc element m>>2 (cndmask select, no
// runtime vector index) -> one gate-triple per lane. Live regs = R1 minus one
// h element: no spill.
#define B_   256
#define T_   128
#define IN_  128
#define H_   256
#define H3_  768
#define OUT_ 128

#define L2E  1.4426950408889634f

typedef unsigned short u16;
typedef u16   u16x2  __attribute__((ext_vector_type(2)));
typedef u16   u16x4  __attribute__((ext_vector_type(4)));
typedef u16   u16x8  __attribute__((ext_vector_type(8)));
typedef __bf16 bf16x8 __attribute__((ext_vector_type(8)));
typedef float f32x2  __attribute__((ext_vector_type(2)));
typedef float f32x4  __attribute__((ext_vector_type(4)));

__device__ __forceinline__ float bf2f(u16 u) {
  unsigned int v = ((unsigned int)u) << 16;
  return __builtin_bit_cast(float, v);
}
__device__ __forceinline__ u16 f2bf(float f) {        // RNE (off hot path)
  unsigned int u = __builtin_bit_cast(unsigned int, f);
  u += 0x7fffu + ((u >> 16) & 1u);
  return (u16)(u >> 16);
}
__device__ __forceinline__ u16 f2bf_fast(float f) {   // round-half-up
  unsigned int u = __builtin_bit_cast(unsigned int, f);
  return (u16)((u + 0x8000u) >> 16);
}
__device__ __forceinline__ f32x4 mfma16(bf16x8 a, bf16x8 b, f32x4 c) {
  return __builtin_amdgcn_mfma_f32_16x16x32_bf16(a, b, c, 0, 0, 0);
}
__device__ __forceinline__ float exp2f_(float x) {
#if __has_builtin(__builtin_amdgcn_exp2f)
  return __builtin_amdgcn_exp2f(x);
#else
  return __builtin_exp2f(x);
#endif
}
__device__ __forceinline__ float rcp_(float x) { return __builtin_amdgcn_rcpf(x); }

// constant-index select of acc element e (avoids runtime vector indexing)
__device__ __forceinline__ float pick4(f32x4 v, int e) {
  float r = v[0];
  r = (e == 1) ? v[1] : r;
  r = (e == 2) ? v[2] : r;
  r = (e == 3) ? v[3] : r;
  return r;
}

// ---------------------------------------------------------------------------
// Kernel 1 (fused prep):
//  blocks [0,384):  Wx (f32, 128x768) -> WxT (bf16, 768x128), unscaled
//  blocks [384,480): Wh (f32, 256x768) -> whp: bf16 fragments PRE-PACKED in
//    the exact per-thread order cru_scan consumes (layout is block-invariant)
__global__ __launch_bounds__(256) void prep(const float* __restrict__ Wx,
                                            const float* __restrict__ Wh,
                                            u16* __restrict__ WxT,
                                            u16* __restrict__ whp) {
  const int bid = blockIdx.x;
  if (bid < 384) {
    int o = bid * 256 + threadIdx.x;            // 0..98303
    int n = o >> 7, k = o & 127;
    WxT[o] = f2bf(Wx[(size_t)k * H3_ + n]);
  } else {
    int o8 = (bid - 384) * 256 + threadIdx.x;   // 0..24575 (one u16x8 each)
    int kk = o8 & 7;
    int g  = (o8 >> 3) % 3;
    int tp = o8 / 24;                           // scan-kernel tid, 0..1023
    int l  = tp & 63, w = tp >> 6;
    int n  = g * 256 + w * 16 + (l & 15);
    int rowb = kk * 32 + (((l >> 4) & 3) << 3);
    float sgw = (g < 2) ? L2E : (2.f * L2E);
    u16x8 v;
    #pragma unroll
    for (int j = 0; j < 8; ++j)
      v[j] = f2bf(Wh[(size_t)(rowb + j) * H3_ + n] * sgw);
    *(u16x8*)(whp + (size_t)o8 * 8) = v;
  }
}

// ---------------------------------------------------------------------------
// Kernel 2: gx[t*B+b][n] = bf16( (x[b,t,:]@Wx[:,n] + bx[n] + (n<512?bh[n]:0)) * sc )
// sc = L2E for r/z gates (n<512), 2*L2E for n gate. M=32768, N=768, K=128.
// Tile 128(M) x 192(N), 512 threads (8 waves as 2Mx4N). C staged via LDS.
__global__ __launch_bounds__(512) void gx_gemm(const float* __restrict__ x,
                                               const u16* __restrict__ WxT,
                                               const float* __restrict__ bx,
                                               const float* __restrict__ bh,
                                               u16* __restrict__ gxw) {
  __shared__ __align__(16) char smem[(128 * 136 + 192 * 136) * 2];  // 87 KB
  u16 (*As)[136] = (u16(*)[136])smem;
  u16 (*Bs)[136] = (u16(*)[136])(smem + 128 * 136 * 2);
  u16 (*St)[204] = (u16(*)[204])smem;       // aliases As/Bs after 2nd barrier

  const int mt = blockIdx.x;                  // 0..255
  const int n0 = blockIdx.y * 192;            // 0,192,384,576
  const int m0 = mt * 128;
  const int t  = mt >> 1;
  const int brow0 = (mt & 1) * 128;
  const int tid = threadIdx.x;
  const int w = tid >> 6, lane = tid & 63, quad = lane >> 4, r = lane & 15;
  const int wm = w >> 2, wn = w & 3;          // 2 x 4 wave grid

  {  // A tile: 128 rows x 128 cols, f32 -> bf16
    int row = tid >> 2;
    int colc = (tid & 3) * 32;
    const float* s = x + ((size_t)(brow0 + row) * T_ + t) * IN_ + colc;
    #pragma unroll
    for (int c4 = 0; c4 < 8; ++c4) {
      f32x4 v = *(const f32x4*)(s + c4 * 4);
      u16x4 b;
      b[0] = f2bf(v[0]); b[1] = f2bf(v[1]); b[2] = f2bf(v[2]); b[3] = f2bf(v[3]);
      *(u16x4*)&As[row][colc + c4 * 4] = b;
    }
  }
  {  // B tile [n][k] from WxT: 192 x 128 u16
    #pragma unroll
    for (int i = 0; i < 6; ++i) {
      int idx = tid + i * 512;                // 0..3071
      int row = idx >> 4, col8 = (idx & 15) * 8;
      *(u16x8*)&Bs[row][col8] = *(const u16x8*)(WxT + (size_t)(n0 + row) * IN_ + col8);
    }
  }
  __syncthreads();

  f32x4 acc[4][3];
  #pragma unroll
  for (int i = 0; i < 4; ++i)
    #pragma unroll
    for (int j = 0; j < 3; ++j)
      acc[i][j] = (f32x4){0.f, 0.f, 0.f, 0.f};

  #pragma unroll
  for (int kk = 0; kk < 4; ++kk) {
    bf16x8 a[4];
    #pragma unroll
    for (int m2 = 0; m2 < 4; ++m2)
      a[m2] = *(const bf16x8*)&As[wm * 64 + m2 * 16 + r][kk * 32 + quad * 8];
    #pragma unroll
    for (int n2 = 0; n2 < 3; ++n2) {
      bf16x8 b = *(const bf16x8*)&Bs[wn * 48 + n2 * 16 + r][kk * 32 + quad * 8];
      #pragma unroll
      for (int m2 = 0; m2 < 4; ++m2)
        acc[m2][n2] = mfma16(a[m2], b, acc[m2][n2]);
    }
  }

  __syncthreads();   // all LDS reads done; safe to alias As/Bs as St

  #pragma unroll
  for (int m2 = 0; m2 < 4; ++m2)
    #pragma unroll
    for (int n2 = 0; n2 < 3; ++n2) {
      int nl = wn * 48 + n2 * 16 + r;                  // local col (C col = lane&15)
      int n  = n0 + nl;
      float sc = (n < 512) ? L2E : (2.f * L2E);
      float bias = bx[n] + (n < 512 ? bh[n] : 0.f);
      #pragma unroll
      for (int e = 0; e < 4; ++e) {                    // C row = quad*4 + e
        int mrow = wm * 64 + m2 * 16 + quad * 4 + e;
        St[mrow][nl] = f2bf((acc[m2][n2][e] + bias) * sc);
      }
    }
  __syncthreads();

  #pragma unroll
  for (int i = 0; i < 6; ++i) {                        // coalesced 16B stores
    int idx = tid + i * 512;                           // 0..3071
    int row = idx / 24, c8 = (idx % 24) * 8;
    *(u16x8*)(gxw + (size_t)(m0 + row) * H3_ + n0 + c8) = *(const u16x8*)&St[row][c8];
  }
}

// ---------------------------------------------------------------------------
// Kernel 3: the scan. 192 blocks x 1024 threads (16 waves), 4 batch rows per
// block (blocks independent across the whole scan; Wh/bh shared).
// h_bf row = 288 u16 (576 B): row bases land on banks {0,16,0,16} -> the
// 16-distinct-address b128 reads are 2-way aliased = free (m136); verified
// conflict-free pattern from R2 (SQ_LDS_BANK_CONFLICT -> 0).
// Per step per thread: 3 scalar gx loads -> 8 ds_read_b128 + 24 MFMA ->
// ONE gate-triple epilogue (cndmask-select acc element) -> 1 ds_write_b16 ->
// one barrier. Fragment file: 96 VGPRs, same pre-packed whp as R=8 (the
// (w,lane)->fragment map is R-invariant).
__global__ __launch_bounds__(1024)
void cru_scan(const float* __restrict__ hid,
              const u16*  __restrict__ whp,
              const float* __restrict__ bh,
              const u16*  __restrict__ gx,
              float* __restrict__ hT) {
  __shared__ __align__(16) u16 h_bf[2][4][288];   // double buffer, 4.6 KB

  const int bid = blockIdx.x;           // 192 blocks
  const int c   = bid >> 6;             // component 0..2
  const int b0  = (bid & 63) << 2;      // batch row group of 4
  const int tid = threadIdx.x;
  const int lane = tid & 63, quad = lane >> 4, m = lane & 15;
  const int w  = tid >> 6;              // wave 0..15
  const int bb = m & 3;                 // batch row within group
  const int e  = m >> 2;                // kept accumulator element
  const int hcol = w * 16 + quad * 4 + e;   // owned n-col 0..255

  // --- one-time fragment load: 384 B contiguous per thread, coalesced ---
  bf16x8 bfr[3][8];
  {
    const u16* wp = whp + (size_t)tid * 192;
    #pragma unroll
    for (int g = 0; g < 3; ++g)
      #pragma unroll
      for (int kk = 0; kk < 8; ++kk)
        bfr[g][kk] = *(const bf16x8*)(wp + g * 64 + kk * 8);
  }

  // --- this lane's h element: h[bb][hcol] ---
  const size_t hrow = (size_t)(c * 256 + b0 + bb) * 256 + hcol;
  float hx = hid[hrow];
  h_bf[0][bb][hcol] = f2bf(hx);
  const float bn0 = bh[512 + hcol] * (2.f * L2E);

  const u16* gxp = gx + (size_t)(b0 + bb) * H3_ + hcol;
  const int rbase = bb * 288 + quad * 8;       // B-frag read base (u16 units)

  __syncthreads();

  #pragma unroll 2
  for (int t = 0; t < T_; ++t) {
    const int sel = t & 1;
    // A) issue this step's gx loads; consumed after the MFMA phase
    const u16* src = gxp + (size_t)t * (B_ * H3_);
    u16 xr = src[0];
    u16 xz = src[256];
    u16 xn = src[512];

    // B) gh^T = Wh^T * h^T  (B cols 4-way batch-duplicated, HW broadcast)
    f32x4 accR = {0.f, 0.f, 0.f, 0.f};
    f32x4 accZ = {0.f, 0.f, 0.f, 0.f};
    f32x4 accN = {0.f, 0.f, 0.f, 0.f};
    const u16* hb = &h_bf[sel][0][0];
    #pragma unroll
    for (int kk = 0; kk < 8; ++kk) {
      bf16x8 hfrag = *(const bf16x8*)(hb + rbase + kk * 32);
      accR = mfma16(bfr[0][kk], hfrag, accR);
      accZ = mfma16(bfr[1][kk], hfrag, accZ);
      accN = mfma16(bfr[2][kk], hfrag, accN);
    }

    // C) epilogue: this lane owns (batch bb, n-col hcol), all three gates
    float gR = pick4(accR, e), gZ = pick4(accZ, e), gN = pick4(accN, e);
    float sr = rcp_(1.f + exp2f_(-(bf2f(xr) + gR)));       // sigmoid
    float sz = rcp_(1.f + exp2f_(-(bf2f(xz) + gZ)));
    float nv = bf2f(xn) + sr * (gN + bn0);                 // 2*L2E-scaled
    float nn = fmaf(2.f, rcp_(1.f + exp2f_(-nv)), -1.f);   // tanh, inf-safe
    float hv = nn + sz * (hx - nn);
    hx = hv;
    h_bf[sel ^ 1][bb][hcol] = f2bf_fast(hv);
    __syncthreads();   // h_bf[sel^1] ready; orders next-step reads of sel
  }

  hT[hrow] = hx;
}

// ---------------------------------------------------------------------------
// Kernel 4: out[b] = elu(sum_c hT[c,b,:] @ Wf + bf); feature[c,:] = mean_b hT
__global__ __launch_bounds__(128) void finalize(const float* __restrict__ hT,
                                                const float* __restrict__ Wf,
                                                const float* __restrict__ bfv,
                                                float* __restrict__ out) {
  __shared__ float hsum[256];
  const int bid = blockIdx.x, tid = threadIdx.x;
  if (bid < 256) {
    const int b = bid;
    for (int k = tid; k < 256; k += 128)
      hsum[k] = hT[((size_t)(0 * 256 + b)) * 256 + k]
              + hT[((size_t)(1 * 256 + b)) * 256 + k]
              + hT[((size_t)(2 * 256 + b)) * 256 + k];
    __syncthreads();
    float acc = bfv[tid];
    #pragma unroll 8
    for (int k = 0; k < 256; ++k)
      acc = fmaf(hsum[k], Wf[(size_t)k * OUT_ + tid], acc);
    float rv = acc > 0.f ? acc : (__expf(acc) - 1.f);
    out[b * OUT_ + tid] = rv;
  } else {
    const int idx = bid - 256;                 // 0..5
    const int c = idx >> 1, j = ((idx & 1) << 7) + tid;
    float sum = 0.f;
    #pragma unroll 4
    for (int b = 0; b < 256; ++b)
      sum += hT[((size_t)(c * 256 + b)) * 256 + j];
    out[B_ * OUT_ + c * 256 + j] = sum * (1.f / 256.f);
  }
}

// ---------------------------------------------------------------------------
extern "C" void kernel_launch(void* const* d_in, const int* in_sizes, int n_in,
                              void* d_out, int out_size, void* d_ws, size_t ws_size,
                              hipStream_t stream) {
  const float* x   = (const float*)d_in[0];
  const float* hid = (const float*)d_in[1];
  const float* Wx  = (const float*)d_in[2];
  const float* bx  = (const float*)d_in[3];
  const float* Wh  = (const float*)d_in[4];
  const float* bh  = (const float*)d_in[5];
  const float* Wf  = (const float*)d_in[6];
  const float* bf_ = (const float*)d_in[7];
  float* out = (float*)d_out;

  char* ws = (char*)d_ws;
  u16* WxT   = (u16*)ws;                                   // 768*128 bf16 = 192 KiB
  u16* gxw   = (u16*)(ws + (1 << 18));                     // 128*256*768 bf16 = 48 MiB
  float* hTw = (float*)(ws + (1 << 18) + (size_t)T_ * B_ * H3_ * 2);  // 3*256*256 f32
  u16* whp   = (u16*)(ws + (1 << 18) + (size_t)T_ * B_ * H3_ * 2
                         + (size_t)3 * 256 * 256 * 4);     // 256*768 bf16 = 384 KiB

  prep<<<480, 256, 0, stream>>>(Wx, Wh, WxT, whp);
  gx_gemm<<<dim3(256, 4), 512, 0, stream>>>(x, WxT, bx, bh, gxw);
  cru_scan<<<192, 1024, 0, stream>>>(hid, whp, bh, gxw, hTw);
  finalize<<<262, 128, 0, stream>>>(hTw, Wf, bf_, out);
}